// Round 4
// baseline (629.084 us; speedup 1.0000x reference)
//
#include <hip/hip_runtime.h>

// GraphSAGE (mean) x3 + per-graph mean pool, MI355X.
// R4: (a) XCD-partitioned CSR build (dst-range segment = blockIdx&7) to kill
// the 17x scattered-write amplification seen in fill_adj (WRITE 69.5MB for a
// 4MB payload); (b) fused gather+MFMA layer kernel (wave owns a 16-node tile,
// gathers column-per-lane, LDS-transpose pad-68, then the verified bf16x3
// MFMA path with W resident in 128 VGPRs) -- removes the 51MB/layer agg
// buffer round trip.

#define DD 64

typedef __attribute__((ext_vector_type(8))) short short8;   // 8 bf16 (4 VGPRs)
typedef __attribute__((ext_vector_type(4))) float f32x4;    // MFMA accumulator

__device__ inline short8 pack4(unsigned a, unsigned b, unsigned c, unsigned d) {
    union { uint4 u; short8 s; } un;
    un.u = make_uint4(a, b, c, d);
    return un.s;
}

// ---------------- CSR build, XCD-partitioned ----------------
// seg = blockIdx&7 follows the round-robin workgroup->XCD mapping, so all
// atomics/stores for dst-range seg stay in one XCD's L2 (perf-only heuristic).
__global__ __launch_bounds__(256) void count_deg(
    const int* __restrict__ dst, int* __restrict__ deg, int E, int N) {
    const int seg    = blockIdx.x & 7;
    const int chunk  = blockIdx.x >> 3;
    const int nchunk = gridDim.x >> 3;
    const int per = (E + nchunk - 1) / nchunk;
    const int lo = chunk * per;
    const int hi = min(lo + per, E);
    const int slo = (int)(((long long)N * seg) >> 3);
    const int shi = (int)(((long long)N * (seg + 1)) >> 3);
    for (int e = lo + threadIdx.x; e < hi; e += 256) {
        const int d = dst[e];
        if (d >= slo && d < shi) atomicAdd(&deg[d], 1);
    }
}

__global__ __launch_bounds__(256) void fill_adj(
    const int* __restrict__ src, const int* __restrict__ dst,
    int* __restrict__ cursor, int* __restrict__ adj, int E, int N) {
    const int seg    = blockIdx.x & 7;
    const int chunk  = blockIdx.x >> 3;
    const int nchunk = gridDim.x >> 3;
    const int per = (E + nchunk - 1) / nchunk;
    const int lo = chunk * per;
    const int hi = min(lo + per, E);
    const int slo = (int)(((long long)N * seg) >> 3);
    const int shi = (int)(((long long)N * (seg + 1)) >> 3);
    for (int e = lo + threadIdx.x; e < hi; e += 256) {
        const int d = dst[e];
        if (d >= slo && d < shi) {
            const int pos = atomicAdd(&cursor[d], 1);
            adj[pos] = src[e];
        }
    }
}

// ---------------- scans (unchanged) ----------------
__global__ void scan1(const int* __restrict__ deg, int* __restrict__ offs,
                      int* __restrict__ bsum, int n) {
    __shared__ int s[1024];
    int t = threadIdx.x;
    int i = blockIdx.x * 1024 + t;
    int v = (i < n) ? deg[i] : 0;
    s[t] = v;
    __syncthreads();
    for (int o = 1; o < 1024; o <<= 1) {
        int a = (t >= o) ? s[t - o] : 0;
        __syncthreads();
        s[t] += a;
        __syncthreads();
    }
    if (i < n) offs[i + 1] = s[t];
    if (t == 1023) bsum[blockIdx.x] = s[t];
    if (blockIdx.x == 0 && t == 0) offs[0] = 0;
}

__global__ void scan2(int* __restrict__ bsum, int nb) {
    __shared__ int s[1024];
    int t = threadIdx.x;
    s[t] = (t < nb) ? bsum[t] : 0;
    __syncthreads();
    for (int o = 1; o < 1024; o <<= 1) {
        int a = (t >= o) ? s[t - o] : 0;
        __syncthreads();
        s[t] += a;
        __syncthreads();
    }
    int ex = (t > 0) ? s[t - 1] : 0;
    if (t < nb) bsum[t] = ex;
}

__global__ void scan3(int* __restrict__ offs, const int* __restrict__ bsum, int n) {
    int i = blockIdx.x * 1024 + threadIdx.x;
    if (i < n) offs[i + 1] += bsum[blockIdx.x];
}

// ---------------- W pre-pack into MFMA B-fragment layout, bf16 hi/lo --------
// B(global) = [Wl ; Wr]  (128 x 64). Frag (ks,nt): lane l holds
// B[ks*32 + (l>>4)*8 + s][nt*16 + (l&15)], s=0..7, packed 2 bf16/dword.
// Bp layout: [layer][hi/lo][fid=ks*4+nt][lane][4 dwords]
__global__ void pack_B(const float* __restrict__ Wl, const float* __restrict__ Wr,
                       unsigned* __restrict__ Bp, int L) {
    int t = blockIdx.x * 256 + threadIdx.x;
    int wv = t >> 6, lane = t & 63;
    if (wv >= L * 16) return;
    int layer = wv >> 4;
    int fid = wv & 15;
    int ks = fid >> 2, nt = fid & 3;
    int j = nt * 16 + (lane & 15);
    int kb = ks * 32 + (lane >> 4) * 8;
    const float* wl = Wl + (size_t)layer * DD * DD;
    const float* wr = Wr + (size_t)layer * DD * DD;
    unsigned hi[8], lo[8];
#pragma unroll
    for (int s = 0; s < 8; ++s) {
        int k = kb + s;
        float v = (k < DD) ? wl[k * DD + j] : wr[(k - DD) * DD + j];
        unsigned u = __float_as_uint(v);
        unsigned h = u & 0xFFFF0000u;
        hi[s] = h;
        float lf = v - __uint_as_float(h);         // exact residual
        lo[s] = __float_as_uint(lf) & 0xFFFF0000u;
    }
    size_t base_hi = ((size_t)(layer * 2 + 0) * 16 + fid) * 64 + lane;
    size_t base_lo = ((size_t)(layer * 2 + 1) * 16 + fid) * 64 + lane;
#pragma unroll
    for (int p = 0; p < 4; ++p) {
        Bp[base_hi * 4 + p] = (hi[2 * p] >> 16) | hi[2 * p + 1];
        Bp[base_lo * 4 + p] = (lo[2 * p] >> 16) | lo[2 * p + 1];
    }
}

// ---------------- fused layer: gather-mean -> LDS transpose -> MFMA ---------
// out = bias + [mean_gather(x) | x] @ [Wl;Wr], bf16x3 split precision.
// Wave owns a 16-node tile; grid-strides. B-frags VGPR-resident.
#define LP 68   // LDS row pitch (floats): 16B-aligned, conflict-free writes
__global__ __launch_bounds__(256, 2) void sage_fused(
    const float* __restrict__ xin, float* __restrict__ out,
    const int* __restrict__ offs, const int* __restrict__ adj,
    const unsigned* __restrict__ Bp, const float* __restrict__ bias, int n) {
    const int lane = threadIdx.x & 63;
    const int wsl  = threadIdx.x >> 6;
    const int wv   = (int)((blockIdx.x * 256 + threadIdx.x) >> 6);
    const int nwv  = (int)((gridDim.x * 256) >> 6);

    __shared__ float lds[4][16 * LP];
    float* myl = lds[wsl];

    short8 Bh[4][4], Bl[4][4];
#pragma unroll
    for (int ks = 0; ks < 4; ++ks)
#pragma unroll
        for (int nt = 0; nt < 4; ++nt) {
            int fid = ks * 4 + nt;
            const uint4 h = *reinterpret_cast<const uint4*>(Bp + ((size_t)fid * 64 + lane) * 4);
            const uint4 l = *reinterpret_cast<const uint4*>(Bp + ((size_t)(16 + fid) * 64 + lane) * 4);
            Bh[ks][nt] = pack4(h.x, h.y, h.z, h.w);
            Bl[ks][nt] = pack4(l.x, l.y, l.z, l.w);
        }

    float bv[4];
#pragma unroll
    for (int nt = 0; nt < 4; ++nt) bv[nt] = bias[nt * 16 + (lane & 15)];

    const int ntiles = (n + 15) >> 4;
    for (int tile = wv; tile < ntiles; tile += nwv) {
        // ---- gather phase: node i's mean, column `lane`, into LDS row i ----
        for (int i = 0; i < 16; ++i) {
            const int nd = tile * 16 + i;
            float a0 = 0.f, a1 = 0.f, a2 = 0.f, a3 = 0.f;
            if (nd < n) {
                const int s = offs[nd];
                const int e = offs[nd + 1];
                int j = s;
                for (; j + 4 <= e; j += 4) {
                    const int i0 = adj[j], i1 = adj[j + 1], i2 = adj[j + 2], i3 = adj[j + 3];
                    a0 += xin[(size_t)i0 * DD + lane];
                    a1 += xin[(size_t)i1 * DD + lane];
                    a2 += xin[(size_t)i2 * DD + lane];
                    a3 += xin[(size_t)i3 * DD + lane];
                }
                for (; j < e; ++j) a0 += xin[(size_t)adj[j] * DD + lane];
                const int dgr = e - s;
                a0 = (a0 + a1 + a2 + a3) * ((dgr > 0) ? (1.0f / (float)dgr) : 1.0f);
            }
            myl[i * LP + lane] = a0;   // banks (4i+lane)%32: 2-way = free
        }
        // per-wave LDS region: in-order wave, compiler inserts lgkmcnt waits

        const int row = tile * 16 + (lane & 15);
        const bool ok = row < n;
        const float* xrow = xin + (size_t)row * DD + (lane >> 4) * 8;
        const float* lrow = myl + (lane & 15) * LP + (lane >> 4) * 8;

        f32x4 acc[4];
#pragma unroll
        for (int nt = 0; nt < 4; ++nt) acc[nt] = (f32x4){bv[nt], bv[nt], bv[nt], bv[nt]};

#pragma unroll
        for (int ks = 0; ks < 4; ++ks) {
            f32x4 v0, v1;
            if (ks < 2) {   // agg half from LDS (zeros for rows >= n)
                v0 = *reinterpret_cast<const f32x4*>(lrow + ks * 32);
                v1 = *reinterpret_cast<const f32x4*>(lrow + ks * 32 + 4);
            } else {        // self half from global
                const float* base = xrow + (ks & 1) * 32;
                v0 = ok ? *reinterpret_cast<const f32x4*>(base)
                        : (f32x4){0.f, 0.f, 0.f, 0.f};
                v1 = ok ? *reinterpret_cast<const f32x4*>(base + 4)
                        : (f32x4){0.f, 0.f, 0.f, 0.f};
            }
            float vv[8] = {v0[0], v0[1], v0[2], v0[3], v1[0], v1[1], v1[2], v1[3]};
            unsigned hu[4], lu[4];
#pragma unroll
            for (int p = 0; p < 4; ++p) {
                unsigned ua = __float_as_uint(vv[2 * p]);
                unsigned ub = __float_as_uint(vv[2 * p + 1]);
                unsigned ha = ua & 0xFFFF0000u, hb = ub & 0xFFFF0000u;
                hu[p] = (ha >> 16) | hb;
                float la = vv[2 * p]     - __uint_as_float(ha);
                float lb = vv[2 * p + 1] - __uint_as_float(hb);
                lu[p] = ((__float_as_uint(la) & 0xFFFF0000u) >> 16) |
                        (__float_as_uint(lb) & 0xFFFF0000u);
            }
            const short8 Ah = pack4(hu[0], hu[1], hu[2], hu[3]);
            const short8 Al = pack4(lu[0], lu[1], lu[2], lu[3]);
#pragma unroll
            for (int nt = 0; nt < 4; ++nt) {
                acc[nt] = __builtin_amdgcn_mfma_f32_16x16x32_bf16(Ah, Bh[ks][nt], acc[nt], 0, 0, 0);
                acc[nt] = __builtin_amdgcn_mfma_f32_16x16x32_bf16(Al, Bh[ks][nt], acc[nt], 0, 0, 0);
                acc[nt] = __builtin_amdgcn_mfma_f32_16x16x32_bf16(Ah, Bl[ks][nt], acc[nt], 0, 0, 0);
            }
        }

        // C/D layout (verified): col = lane&15, row = (lane>>4)*4 + reg
        const int r0 = tile * 16 + (lane >> 4) * 4;
#pragma unroll
        for (int r = 0; r < 4; ++r) {
            const int rr = r0 + r;
            if (rr < n) {
#pragma unroll
                for (int nt = 0; nt < 4; ++nt)
                    out[(size_t)rr * DD + nt * 16 + (lane & 15)] = acc[nt][r];
            }
        }
    }
}

// ---------------- pooling: grid-wide partials + finalize ----------------
__global__ void pool_partial(const float* __restrict__ x, const int* __restrict__ batch,
                             float* __restrict__ sums, int n) {
    const int lane = threadIdx.x & 63;
    const int wv   = (int)((blockIdx.x * blockDim.x + threadIdx.x) >> 6);
    const int nwv  = (int)((gridDim.x * blockDim.x) >> 6);
    const int chunk = (n + nwv - 1) / nwv;
    const int start = wv * chunk;
    if (start >= n) return;
    const int end = min(start + chunk, n);

    int g = batch[start];
    float acc = 0.f;
    for (int nd = start; nd < end; ++nd) {
        const int bg = batch[nd];
        if (bg != g) {
            atomicAdd(&sums[(size_t)g * DD + lane], acc);
            acc = 0.f;
            g = bg;
        }
        acc += x[(size_t)nd * DD + lane];
    }
    atomicAdd(&sums[(size_t)g * DD + lane], acc);
}

__global__ void pool_final(const float* __restrict__ sums, const int* __restrict__ batch,
                           float* __restrict__ out, int n) {
    const int g = blockIdx.x;
    const int t = threadIdx.x;  // 64 threads
    int lo = 0, hi = n;
    while (lo < hi) { int m = (lo + hi) >> 1; if (batch[m] < g) lo = m + 1; else hi = m; }
    const int st = lo;
    lo = 0; hi = n;
    while (lo < hi) { int m = (lo + hi) >> 1; if (batch[m] < g + 1) lo = m + 1; else hi = m; }
    const int c = lo - st;
    out[(size_t)g * DD + t] = sums[(size_t)g * DD + t] / (float)((c > 0) ? c : 1);
}

extern "C" void kernel_launch(void* const* d_in, const int* in_sizes, int n_in,
                              void* d_out, int out_size, void* d_ws, size_t ws_size,
                              hipStream_t stream) {
    const float* x     = (const float*)d_in[0];
    const int*   ei    = (const int*)d_in[1];
    const int*   batch = (const int*)d_in[2];
    const float* Wl    = (const float*)d_in[3];
    const float* bl    = (const float*)d_in[4];
    const float* Wr    = (const float*)d_in[5];

    const int N = in_sizes[0] / DD;
    const int E = in_sizes[1] / 2;
    const int L = in_sizes[3] / (DD * DD);
    const int G = out_size / DD;

    const int* src = ei;        // edge_index[0]
    const int* dst = ei + E;    // edge_index[1]

    char* ws = (char*)d_ws;
    size_t off = 0;
    auto alloc = [&](size_t bytes) -> char* {
        char* p = ws + off;
        off += (bytes + 255) & ~(size_t)255;
        return p;
    };
    int*      deg    = (int*)alloc((size_t)N * 4);
    int*      offs   = (int*)alloc((size_t)(N + 1) * 4);
    int*      cursor = (int*)alloc((size_t)N * 4);
    int*      adj    = (int*)alloc((size_t)E * 4);
    int*      bsum   = (int*)alloc(1024 * 4);
    float*    b0     = (float*)alloc((size_t)N * DD * 4);
    float*    b1     = (float*)alloc((size_t)N * DD * 4);
    unsigned* Bp     = (unsigned*)alloc((size_t)L * 2 * 16 * 64 * 4 * 4);
    float*    sums   = (float*)alloc((size_t)G * DD * 4);

    // ---- CSR build, XCD-partitioned (graph reused by all layers) ----
    hipMemsetAsync(deg, 0, (size_t)N * 4, stream);
    count_deg<<<4096, 256, 0, stream>>>(dst, deg, E, N);
    const int nb = (N + 1023) / 1024;
    scan1<<<nb, 1024, 0, stream>>>(deg, offs, bsum, N);
    scan2<<<1, 1024, 0, stream>>>(bsum, nb);
    scan3<<<nb, 1024, 0, stream>>>(offs, bsum, N);
    hipMemcpyAsync(cursor, offs, (size_t)N * 4, hipMemcpyDeviceToDevice, stream);
    fill_adj<<<4096, 256, 0, stream>>>(src, dst, cursor, adj, E, N);

    // ---- pack W into MFMA fragment layout (all layers) ----
    pack_B<<<(L * 16 * 64 + 255) / 256, 256, 0, stream>>>(Wl, Wr, Bp, L);

    // ---- fused layers (ping-pong) ----
    const float* cur = x;
    float* bufs[2] = {b0, b1};
    for (int l = 0; l < L; ++l) {
        float* outb = bufs[l & 1];
        sage_fused<<<512, 256, 0, stream>>>(cur, outb, offs, adj,
                                            Bp + (size_t)l * 2 * 16 * 64 * 4,
                                            bl + (size_t)l * DD, N);
        cur = outb;
    }

    // ---- per-graph mean pool: partials + finalize ----
    hipMemsetAsync(sums, 0, (size_t)G * DD * 4, stream);
    pool_partial<<<256, 256, 0, stream>>>(cur, batch, sums, N);
    pool_final<<<G, DD, 0, stream>>>(sums, batch, (float*)d_out, N);
}

// Round 5
// 319.122 us; speedup vs baseline: 1.9713x; 1.9713x over previous
//
#include <hip/hip_runtime.h>

// GraphSAGE (mean) x3 + per-graph mean pool, MI355X.
// R5: revert R4's fusion (occupancy-capped the latency-bound gather); keep
// XCD-partitioned CSR build. New: pooling is linear, so the LAST layer needs
// no per-node GEMM: mean_g(x3) = mean_g(agg3)@Wl + mean_g(x2)@Wr + b.

#define DD 64

typedef __attribute__((ext_vector_type(8))) short short8;   // 8 bf16 (4 VGPRs)
typedef __attribute__((ext_vector_type(4))) float f32x4;    // MFMA accumulator

__device__ inline short8 pack4(unsigned a, unsigned b, unsigned c, unsigned d) {
    union { uint4 u; short8 s; } un;
    un.u = make_uint4(a, b, c, d);
    return un.s;
}

// ---------------- CSR build, XCD-partitioned ----------------
// seg = blockIdx&7 matches the round-robin workgroup->XCD mapping, so all
// atomics/adj stores for one dst-range stay in one XCD's L2 (kills the 17x
// scattered-write amplification seen in R3: WRITE 69.5MB for 4MB payload).
__global__ __launch_bounds__(256) void count_deg(
    const int* __restrict__ dst, int* __restrict__ deg, int E, int N) {
    const int seg    = blockIdx.x & 7;
    const int chunk  = blockIdx.x >> 3;
    const int nchunk = gridDim.x >> 3;
    const int per = (E + nchunk - 1) / nchunk;
    const int lo = chunk * per;
    const int hi = min(lo + per, E);
    const int slo = (int)(((long long)N * seg) >> 3);
    const int shi = (int)(((long long)N * (seg + 1)) >> 3);
    for (int e = lo + threadIdx.x; e < hi; e += 256) {
        const int d = dst[e];
        if (d >= slo && d < shi) atomicAdd(&deg[d], 1);
    }
}

__global__ __launch_bounds__(256) void fill_adj(
    const int* __restrict__ src, const int* __restrict__ dst,
    int* __restrict__ cursor, int* __restrict__ adj, int E, int N) {
    const int seg    = blockIdx.x & 7;
    const int chunk  = blockIdx.x >> 3;
    const int nchunk = gridDim.x >> 3;
    const int per = (E + nchunk - 1) / nchunk;
    const int lo = chunk * per;
    const int hi = min(lo + per, E);
    const int slo = (int)(((long long)N * seg) >> 3);
    const int shi = (int)(((long long)N * (seg + 1)) >> 3);
    for (int e = lo + threadIdx.x; e < hi; e += 256) {
        const int d = dst[e];
        if (d >= slo && d < shi) {
            const int pos = atomicAdd(&cursor[d], 1);
            adj[pos] = src[e];
        }
    }
}

// ---------------- scans ----------------
__global__ void scan1(const int* __restrict__ deg, int* __restrict__ offs,
                      int* __restrict__ bsum, int n) {
    __shared__ int s[1024];
    int t = threadIdx.x;
    int i = blockIdx.x * 1024 + t;
    int v = (i < n) ? deg[i] : 0;
    s[t] = v;
    __syncthreads();
    for (int o = 1; o < 1024; o <<= 1) {
        int a = (t >= o) ? s[t - o] : 0;
        __syncthreads();
        s[t] += a;
        __syncthreads();
    }
    if (i < n) offs[i + 1] = s[t];
    if (t == 1023) bsum[blockIdx.x] = s[t];
    if (blockIdx.x == 0 && t == 0) offs[0] = 0;
}

__global__ void scan2(int* __restrict__ bsum, int nb) {
    __shared__ int s[1024];
    int t = threadIdx.x;
    s[t] = (t < nb) ? bsum[t] : 0;
    __syncthreads();
    for (int o = 1; o < 1024; o <<= 1) {
        int a = (t >= o) ? s[t - o] : 0;
        __syncthreads();
        s[t] += a;
        __syncthreads();
    }
    int ex = (t > 0) ? s[t - 1] : 0;
    if (t < nb) bsum[t] = ex;
}

__global__ void scan3(int* __restrict__ offs, const int* __restrict__ bsum, int n) {
    int i = blockIdx.x * 1024 + threadIdx.x;
    if (i < n) offs[i + 1] += bsum[blockIdx.x];
}

// ---------------- gather-mean (16 threads/node, float4 chunks) --------------
// Latency-bound: one-shot grid (25k waves), 4 outstanding 16B loads/thread.
__global__ __launch_bounds__(256) void aggregate(
    const float* __restrict__ xin, float* __restrict__ agg,
    const int* __restrict__ offs, const int* __restrict__ adj, int n) {
    const int t  = blockIdx.x * 256 + threadIdx.x;
    const int nd = t >> 4;
    const int c  = (t & 15) * 4;
    if (nd >= n) return;

    const int s = offs[nd];
    const int e = offs[nd + 1];

    float4 a0 = {0.f, 0.f, 0.f, 0.f};
    float4 a1 = {0.f, 0.f, 0.f, 0.f};
    float4 a2 = {0.f, 0.f, 0.f, 0.f};
    float4 a3 = {0.f, 0.f, 0.f, 0.f};

    int j = s;
    for (; j + 4 <= e; j += 4) {
        const int i0 = adj[j], i1 = adj[j + 1], i2 = adj[j + 2], i3 = adj[j + 3];
        const float4 v0 = *reinterpret_cast<const float4*>(xin + (size_t)i0 * DD + c);
        const float4 v1 = *reinterpret_cast<const float4*>(xin + (size_t)i1 * DD + c);
        const float4 v2 = *reinterpret_cast<const float4*>(xin + (size_t)i2 * DD + c);
        const float4 v3 = *reinterpret_cast<const float4*>(xin + (size_t)i3 * DD + c);
        a0.x += v0.x; a0.y += v0.y; a0.z += v0.z; a0.w += v0.w;
        a1.x += v1.x; a1.y += v1.y; a1.z += v1.z; a1.w += v1.w;
        a2.x += v2.x; a2.y += v2.y; a2.z += v2.z; a2.w += v2.w;
        a3.x += v3.x; a3.y += v3.y; a3.z += v3.z; a3.w += v3.w;
    }
    for (; j < e; ++j) {
        const float4 v = *reinterpret_cast<const float4*>(xin + (size_t)adj[j] * DD + c);
        a0.x += v.x; a0.y += v.y; a0.z += v.z; a0.w += v.w;
    }

    const int deg = e - s;
    const float inv = (deg > 0) ? (1.0f / (float)deg) : 1.0f;
    float4 r;
    r.x = (a0.x + a1.x + a2.x + a3.x) * inv;
    r.y = (a0.y + a1.y + a2.y + a3.y) * inv;
    r.z = (a0.z + a1.z + a2.z + a3.z) * inv;
    r.w = (a0.w + a1.w + a2.w + a3.w) * inv;
    *reinterpret_cast<float4*>(agg + (size_t)nd * DD + c) = r;
}

// ---------------- W pre-pack into MFMA B-fragment layout, bf16 hi/lo --------
// B(global) = [Wl ; Wr]  (128 x 64). Frag (ks,nt): lane l holds
// B[ks*32 + (l>>4)*8 + s][nt*16 + (l&15)], s=0..7, packed 2 bf16/dword.
// Bp layout: [layer][hi/lo][fid=ks*4+nt][lane][4 dwords]
__global__ void pack_B(const float* __restrict__ Wl, const float* __restrict__ Wr,
                       unsigned* __restrict__ Bp, int L) {
    int t = blockIdx.x * 256 + threadIdx.x;
    int wv = t >> 6, lane = t & 63;
    if (wv >= L * 16) return;
    int layer = wv >> 4;
    int fid = wv & 15;
    int ks = fid >> 2, nt = fid & 3;
    int j = nt * 16 + (lane & 15);
    int kb = ks * 32 + (lane >> 4) * 8;
    const float* wl = Wl + (size_t)layer * DD * DD;
    const float* wr = Wr + (size_t)layer * DD * DD;
    unsigned hi[8], lo[8];
#pragma unroll
    for (int s = 0; s < 8; ++s) {
        int k = kb + s;
        float v = (k < DD) ? wl[k * DD + j] : wr[(k - DD) * DD + j];
        unsigned u = __float_as_uint(v);
        unsigned h = u & 0xFFFF0000u;
        hi[s] = h;
        float lf = v - __uint_as_float(h);         // exact residual
        lo[s] = __float_as_uint(lf) & 0xFFFF0000u;
    }
    size_t base_hi = ((size_t)(layer * 2 + 0) * 16 + fid) * 64 + lane;
    size_t base_lo = ((size_t)(layer * 2 + 1) * 16 + fid) * 64 + lane;
#pragma unroll
    for (int p = 0; p < 4; ++p) {
        Bp[base_hi * 4 + p] = (hi[2 * p] >> 16) | hi[2 * p + 1];
        Bp[base_lo * 4 + p] = (lo[2 * p] >> 16) | lo[2 * p + 1];
    }
}

// ---------------- layer GEMM: out = bias + [agg|x] @ [Wl;Wr], MFMA bf16x3 ---
__global__ __launch_bounds__(256, 2) void mfma_gemm(
    const float* __restrict__ g, const float* __restrict__ x,
    float* __restrict__ out, const unsigned* __restrict__ Bp,
    const float* __restrict__ bias, int n) {
    const int lane = threadIdx.x & 63;
    const int wv   = (int)((blockIdx.x * 256 + threadIdx.x) >> 6);
    const int nwv  = (int)((gridDim.x * 256) >> 6);

    short8 Bh[4][4], Bl[4][4];
#pragma unroll
    for (int ks = 0; ks < 4; ++ks)
#pragma unroll
        for (int nt = 0; nt < 4; ++nt) {
            int fid = ks * 4 + nt;
            const uint4 h = *reinterpret_cast<const uint4*>(Bp + ((size_t)fid * 64 + lane) * 4);
            const uint4 l = *reinterpret_cast<const uint4*>(Bp + ((size_t)(16 + fid) * 64 + lane) * 4);
            Bh[ks][nt] = pack4(h.x, h.y, h.z, h.w);
            Bl[ks][nt] = pack4(l.x, l.y, l.z, l.w);
        }

    float bv[4];
#pragma unroll
    for (int nt = 0; nt < 4; ++nt) bv[nt] = bias[nt * 16 + (lane & 15)];

    const int ntiles = (n + 15) >> 4;
    for (int tile = wv; tile < ntiles; tile += nwv) {
        const int row = tile * 16 + (lane & 15);
        const bool ok = row < n;
        const float* grow = g + (size_t)row * DD + (lane >> 4) * 8;
        const float* xrow = x + (size_t)row * DD + (lane >> 4) * 8;

        f32x4 acc[4];
#pragma unroll
        for (int nt = 0; nt < 4; ++nt) acc[nt] = (f32x4){bv[nt], bv[nt], bv[nt], bv[nt]};

#pragma unroll
        for (int ks = 0; ks < 4; ++ks) {
            const float* base = ((ks < 2) ? grow : xrow) + (ks & 1) * 32;
            f32x4 v0 = ok ? *reinterpret_cast<const f32x4*>(base)
                          : (f32x4){0.f, 0.f, 0.f, 0.f};
            f32x4 v1 = ok ? *reinterpret_cast<const f32x4*>(base + 4)
                          : (f32x4){0.f, 0.f, 0.f, 0.f};
            float vv[8] = {v0[0], v0[1], v0[2], v0[3], v1[0], v1[1], v1[2], v1[3]};
            unsigned hu[4], lu[4];
#pragma unroll
            for (int p = 0; p < 4; ++p) {
                unsigned ua = __float_as_uint(vv[2 * p]);
                unsigned ub = __float_as_uint(vv[2 * p + 1]);
                unsigned ha = ua & 0xFFFF0000u, hb = ub & 0xFFFF0000u;
                hu[p] = (ha >> 16) | hb;
                float la = vv[2 * p]     - __uint_as_float(ha);
                float lb = vv[2 * p + 1] - __uint_as_float(hb);
                lu[p] = ((__float_as_uint(la) & 0xFFFF0000u) >> 16) |
                        (__float_as_uint(lb) & 0xFFFF0000u);
            }
            const short8 Ah = pack4(hu[0], hu[1], hu[2], hu[3]);
            const short8 Al = pack4(lu[0], lu[1], lu[2], lu[3]);
#pragma unroll
            for (int nt = 0; nt < 4; ++nt) {
                acc[nt] = __builtin_amdgcn_mfma_f32_16x16x32_bf16(Ah, Bh[ks][nt], acc[nt], 0, 0, 0);
                acc[nt] = __builtin_amdgcn_mfma_f32_16x16x32_bf16(Al, Bh[ks][nt], acc[nt], 0, 0, 0);
                acc[nt] = __builtin_amdgcn_mfma_f32_16x16x32_bf16(Ah, Bl[ks][nt], acc[nt], 0, 0, 0);
            }
        }

        // C/D layout (verified): col = lane&15, row = (lane>>4)*4 + reg
        const int r0 = tile * 16 + (lane >> 4) * 4;
#pragma unroll
        for (int r = 0; r < 4; ++r) {
            const int rr = r0 + r;
            if (rr < n) {
#pragma unroll
                for (int nt = 0; nt < 4; ++nt)
                    out[(size_t)rr * DD + nt * 16 + (lane & 15)] = acc[nt][r];
            }
        }
    }
}

// ---------------- pooling partials over TWO arrays at once ----------------
__global__ void pool_partial2(const float* __restrict__ xa, const float* __restrict__ xb,
                              const int* __restrict__ batch,
                              float* __restrict__ sumsA, float* __restrict__ sumsB, int n) {
    const int lane = threadIdx.x & 63;
    const int wv   = (int)((blockIdx.x * blockDim.x + threadIdx.x) >> 6);
    const int nwv  = (int)((gridDim.x * blockDim.x) >> 6);
    const int chunk = (n + nwv - 1) / nwv;
    const int start = wv * chunk;
    if (start >= n) return;
    const int end = min(start + chunk, n);

    int g = batch[start];
    float accA = 0.f, accB = 0.f;
    for (int nd = start; nd < end; ++nd) {
        const int bg = batch[nd];
        if (bg != g) {
            atomicAdd(&sumsA[(size_t)g * DD + lane], accA);
            atomicAdd(&sumsB[(size_t)g * DD + lane], accB);
            accA = 0.f; accB = 0.f;
            g = bg;
        }
        accA += xa[(size_t)nd * DD + lane];
        accB += xb[(size_t)nd * DD + lane];
    }
    atomicAdd(&sumsA[(size_t)g * DD + lane], accA);
    atomicAdd(&sumsB[(size_t)g * DD + lane], accB);
}

// ---------------- final: out[g] = mean(agg3)@Wl + mean(x2)@Wr + b ----------
__global__ void final_gemm(const float* __restrict__ sumsA, const float* __restrict__ sumsX,
                           const int* __restrict__ batch,
                           const float* __restrict__ Wl, const float* __restrict__ bl,
                           const float* __restrict__ Wr,
                           float* __restrict__ out, int n) {
    const int g = blockIdx.x;
    const int d = threadIdx.x;  // 64 threads

    int lo = 0, hi = n;
    while (lo < hi) { int m = (lo + hi) >> 1; if (batch[m] < g) lo = m + 1; else hi = m; }
    const int st = lo;
    lo = 0; hi = n;
    while (lo < hi) { int m = (lo + hi) >> 1; if (batch[m] < g + 1) lo = m + 1; else hi = m; }
    const int c = lo - st;

    if (c == 0) {                    // reference: empty graph -> 0 (not bias)
        out[(size_t)g * DD + d] = 0.f;
        return;
    }
    const float inv = 1.0f / (float)c;

    __shared__ float sa[DD], sx[DD];
    sa[d] = sumsA[(size_t)g * DD + d] * inv;
    sx[d] = sumsX[(size_t)g * DD + d] * inv;
    __syncthreads();

    float acc = bl[d];
#pragma unroll 8
    for (int k = 0; k < DD; ++k) acc += sa[k] * Wl[k * DD + d];
#pragma unroll 8
    for (int k = 0; k < DD; ++k) acc += sx[k] * Wr[k * DD + d];
    out[(size_t)g * DD + d] = acc;
}

extern "C" void kernel_launch(void* const* d_in, const int* in_sizes, int n_in,
                              void* d_out, int out_size, void* d_ws, size_t ws_size,
                              hipStream_t stream) {
    const float* x     = (const float*)d_in[0];
    const int*   ei    = (const int*)d_in[1];
    const int*   batch = (const int*)d_in[2];
    const float* Wl    = (const float*)d_in[3];
    const float* bl    = (const float*)d_in[4];
    const float* Wr    = (const float*)d_in[5];

    const int N = in_sizes[0] / DD;
    const int E = in_sizes[1] / 2;
    const int L = in_sizes[3] / (DD * DD);
    const int G = out_size / DD;

    const int* src = ei;        // edge_index[0]
    const int* dst = ei + E;    // edge_index[1]

    char* ws = (char*)d_ws;
    size_t off = 0;
    auto alloc = [&](size_t bytes) -> char* {
        char* p = ws + off;
        off += (bytes + 255) & ~(size_t)255;
        return p;
    };
    int*      deg    = (int*)alloc((size_t)N * 4);
    int*      offs   = (int*)alloc((size_t)(N + 1) * 4);
    int*      cursor = (int*)alloc((size_t)N * 4);
    int*      adj    = (int*)alloc((size_t)E * 4);
    int*      bsum   = (int*)alloc(1024 * 4);
    float*    b0     = (float*)alloc((size_t)N * DD * 4);
    float*    b1     = (float*)alloc((size_t)N * DD * 4);
    float*    aggbuf = (float*)alloc((size_t)N * DD * 4);
    unsigned* Bp     = (unsigned*)alloc((size_t)L * 2 * 16 * 64 * 4 * 4);
    float*    sumsA  = (float*)alloc((size_t)G * DD * 4);
    float*    sumsX  = (float*)alloc((size_t)G * DD * 4);

    // ---- CSR build, XCD-partitioned (graph reused by all layers) ----
    hipMemsetAsync(deg, 0, (size_t)N * 4, stream);
    count_deg<<<4096, 256, 0, stream>>>(dst, deg, E, N);
    const int nb = (N + 1023) / 1024;
    scan1<<<nb, 1024, 0, stream>>>(deg, offs, bsum, N);
    scan2<<<1, 1024, 0, stream>>>(bsum, nb);
    scan3<<<nb, 1024, 0, stream>>>(offs, bsum, N);
    hipMemcpyAsync(cursor, offs, (size_t)N * 4, hipMemcpyDeviceToDevice, stream);
    fill_adj<<<4096, 256, 0, stream>>>(src, dst, cursor, adj, E, N);

    // ---- pack W into MFMA fragment layout (all layers) ----
    pack_B<<<(L * 16 * 64 + 255) / 256, 256, 0, stream>>>(Wl, Wr, Bp, L);

    // ---- layers 0..L-2: aggregate + MFMA gemm (ping-pong) ----
    const int agg_blocks = (N * 16 + 255) / 256;
    const float* cur = x;
    float* bufs[2] = {b0, b1};
    for (int l = 0; l < L - 1; ++l) {
        float* outb = bufs[l & 1];
        aggregate<<<agg_blocks, 256, 0, stream>>>(cur, aggbuf, offs, adj, N);
        mfma_gemm<<<1024, 256, 0, stream>>>(aggbuf, cur, outb,
                                            Bp + (size_t)l * 2 * 16 * 64 * 4,
                                            bl + (size_t)l * DD, N);
        cur = outb;
    }

    // ---- last layer: pooling is linear -> pool(agg), pool(x), tiny GEMM ----
    aggregate<<<agg_blocks, 256, 0, stream>>>(cur, aggbuf, offs, adj, N);
    hipMemsetAsync(sumsA, 0, (size_t)G * DD * 4, stream);
    hipMemsetAsync(sumsX, 0, (size_t)G * DD * 4, stream);
    pool_partial2<<<256, 256, 0, stream>>>(aggbuf, cur, batch, sumsA, sumsX, N);
    final_gemm<<<G, DD, 0, stream>>>(sumsA, sumsX, batch,
                                     Wl + (size_t)(L - 1) * DD * DD,
                                     bl + (size_t)(L - 1) * DD,
                                     Wr + (size_t)(L - 1) * DD * DD,
                                     (float*)d_out, N);
}

// Round 6
// 263.156 us; speedup vs baseline: 2.3905x; 1.2127x over previous
//
#include <hip/hip_runtime.h>

// GraphSAGE (mean) x3 + per-graph mean pool, MI355X.
// R6: (a) pool_partial2 grid 256->2048 blocks (was 8% occupancy, 47us for a
// 51MB stream); (b) bf16 gather path: gemm epilogue emits an RNE bf16 copy of
// its output, aggregate gathers bf16 rows (halves the 256MB/layer gathered
// traffic), accumulates fp32. Fallback to fp32 gather if ws_size is small.

#define DD 64

typedef __attribute__((ext_vector_type(8))) short short8;   // 8 bf16 (4 VGPRs)
typedef __attribute__((ext_vector_type(4))) float f32x4;    // MFMA accumulator

__device__ inline short8 pack4(unsigned a, unsigned b, unsigned c, unsigned d) {
    union { uint4 u; short8 s; } un;
    un.u = make_uint4(a, b, c, d);
    return un.s;
}

__device__ inline unsigned rne_bf16(float v) {   // round-to-nearest-even, high16
    unsigned u = __float_as_uint(v);
    return (u + 0x7FFFu + ((u >> 16) & 1u)) >> 16;
}

// ---------------- CSR build, XCD-partitioned ----------------
__global__ __launch_bounds__(256) void count_deg(
    const int* __restrict__ dst, int* __restrict__ deg, int E, int N) {
    const int seg    = blockIdx.x & 7;
    const int chunk  = blockIdx.x >> 3;
    const int nchunk = gridDim.x >> 3;
    const int per = (E + nchunk - 1) / nchunk;
    const int lo = chunk * per;
    const int hi = min(lo + per, E);
    const int slo = (int)(((long long)N * seg) >> 3);
    const int shi = (int)(((long long)N * (seg + 1)) >> 3);
    for (int e = lo + threadIdx.x; e < hi; e += 256) {
        const int d = dst[e];
        if (d >= slo && d < shi) atomicAdd(&deg[d], 1);
    }
}

__global__ __launch_bounds__(256) void fill_adj(
    const int* __restrict__ src, const int* __restrict__ dst,
    int* __restrict__ cursor, int* __restrict__ adj, int E, int N) {
    const int seg    = blockIdx.x & 7;
    const int chunk  = blockIdx.x >> 3;
    const int nchunk = gridDim.x >> 3;
    const int per = (E + nchunk - 1) / nchunk;
    const int lo = chunk * per;
    const int hi = min(lo + per, E);
    const int slo = (int)(((long long)N * seg) >> 3);
    const int shi = (int)(((long long)N * (seg + 1)) >> 3);
    for (int e = lo + threadIdx.x; e < hi; e += 256) {
        const int d = dst[e];
        if (d >= slo && d < shi) {
            const int pos = atomicAdd(&cursor[d], 1);
            adj[pos] = src[e];
        }
    }
}

// ---------------- scans ----------------
__global__ void scan1(const int* __restrict__ deg, int* __restrict__ offs,
                      int* __restrict__ bsum, int n) {
    __shared__ int s[1024];
    int t = threadIdx.x;
    int i = blockIdx.x * 1024 + t;
    int v = (i < n) ? deg[i] : 0;
    s[t] = v;
    __syncthreads();
    for (int o = 1; o < 1024; o <<= 1) {
        int a = (t >= o) ? s[t - o] : 0;
        __syncthreads();
        s[t] += a;
        __syncthreads();
    }
    if (i < n) offs[i + 1] = s[t];
    if (t == 1023) bsum[blockIdx.x] = s[t];
    if (blockIdx.x == 0 && t == 0) offs[0] = 0;
}

__global__ void scan2(int* __restrict__ bsum, int nb) {
    __shared__ int s[1024];
    int t = threadIdx.x;
    s[t] = (t < nb) ? bsum[t] : 0;
    __syncthreads();
    for (int o = 1; o < 1024; o <<= 1) {
        int a = (t >= o) ? s[t - o] : 0;
        __syncthreads();
        s[t] += a;
        __syncthreads();
    }
    int ex = (t > 0) ? s[t - 1] : 0;
    if (t < nb) bsum[t] = ex;
}

__global__ void scan3(int* __restrict__ offs, const int* __restrict__ bsum, int n) {
    int i = blockIdx.x * 1024 + threadIdx.x;
    if (i < n) offs[i + 1] += bsum[blockIdx.x];
}

// ---------------- fp32 -> bf16 (RNE) cast, 8 elems/thread ----------------
__global__ __launch_bounds__(256) void cast_bf16(
    const float* __restrict__ in, unsigned short* __restrict__ outb, long long n8) {
    const long long t = (long long)blockIdx.x * 256 + threadIdx.x;
    if (t >= n8) return;
    const float4 v0 = *reinterpret_cast<const float4*>(in + t * 8);
    const float4 v1 = *reinterpret_cast<const float4*>(in + t * 8 + 4);
    uint4 o;
    o.x = rne_bf16(v0.x) | (rne_bf16(v0.y) << 16);
    o.y = rne_bf16(v0.z) | (rne_bf16(v0.w) << 16);
    o.z = rne_bf16(v1.x) | (rne_bf16(v1.y) << 16);
    o.w = rne_bf16(v1.z) | (rne_bf16(v1.w) << 16);
    *reinterpret_cast<uint4*>(outb + t * 8) = o;
}

// ---------------- gather-mean from bf16 rows (8 threads/node) --------------
// Each thread owns 8 dims (one uint4 = 8 bf16 per edge). fp32 accumulate.
__global__ __launch_bounds__(256) void aggregate_bf16(
    const unsigned short* __restrict__ xb, float* __restrict__ agg,
    const int* __restrict__ offs, const int* __restrict__ adj, int n) {
    const int t  = blockIdx.x * 256 + threadIdx.x;
    const int nd = t >> 3;
    const int c8 = (t & 7) * 8;
    if (nd >= n) return;

    const int s = offs[nd];
    const int e = offs[nd + 1];

    float a0[8], a1[8], a2[8], a3[8];
#pragma unroll
    for (int p = 0; p < 8; ++p) { a0[p] = 0.f; a1[p] = 0.f; a2[p] = 0.f; a3[p] = 0.f; }

#define ACC8(A, U)                                                             \
    do {                                                                       \
        A[0] += __uint_as_float((U).x << 16);                                  \
        A[1] += __uint_as_float((U).x & 0xFFFF0000u);                          \
        A[2] += __uint_as_float((U).y << 16);                                  \
        A[3] += __uint_as_float((U).y & 0xFFFF0000u);                          \
        A[4] += __uint_as_float((U).z << 16);                                  \
        A[5] += __uint_as_float((U).z & 0xFFFF0000u);                          \
        A[6] += __uint_as_float((U).w << 16);                                  \
        A[7] += __uint_as_float((U).w & 0xFFFF0000u);                          \
    } while (0)

    int j = s;
    for (; j + 4 <= e; j += 4) {
        const int i0 = adj[j], i1 = adj[j + 1], i2 = adj[j + 2], i3 = adj[j + 3];
        const uint4 u0 = *reinterpret_cast<const uint4*>(xb + (size_t)i0 * DD + c8);
        const uint4 u1 = *reinterpret_cast<const uint4*>(xb + (size_t)i1 * DD + c8);
        const uint4 u2 = *reinterpret_cast<const uint4*>(xb + (size_t)i2 * DD + c8);
        const uint4 u3 = *reinterpret_cast<const uint4*>(xb + (size_t)i3 * DD + c8);
        ACC8(a0, u0); ACC8(a1, u1); ACC8(a2, u2); ACC8(a3, u3);
    }
    for (; j < e; ++j) {
        const uint4 u = *reinterpret_cast<const uint4*>(xb + (size_t)adj[j] * DD + c8);
        ACC8(a0, u);
    }
#undef ACC8

    const int deg = e - s;
    const float inv = (deg > 0) ? (1.0f / (float)deg) : 1.0f;
    float4 r0, r1;
    r0.x = (a0[0] + a1[0] + a2[0] + a3[0]) * inv;
    r0.y = (a0[1] + a1[1] + a2[1] + a3[1]) * inv;
    r0.z = (a0[2] + a1[2] + a2[2] + a3[2]) * inv;
    r0.w = (a0[3] + a1[3] + a2[3] + a3[3]) * inv;
    r1.x = (a0[4] + a1[4] + a2[4] + a3[4]) * inv;
    r1.y = (a0[5] + a1[5] + a2[5] + a3[5]) * inv;
    r1.z = (a0[6] + a1[6] + a2[6] + a3[6]) * inv;
    r1.w = (a0[7] + a1[7] + a2[7] + a3[7]) * inv;
    *reinterpret_cast<float4*>(agg + (size_t)nd * DD + c8)     = r0;
    *reinterpret_cast<float4*>(agg + (size_t)nd * DD + c8 + 4) = r1;
}

// ---------------- fp32 gather fallback (16 threads/node) ----------------
__global__ __launch_bounds__(256) void aggregate(
    const float* __restrict__ xin, float* __restrict__ agg,
    const int* __restrict__ offs, const int* __restrict__ adj, int n) {
    const int t  = blockIdx.x * 256 + threadIdx.x;
    const int nd = t >> 4;
    const int c  = (t & 15) * 4;
    if (nd >= n) return;
    const int s = offs[nd];
    const int e = offs[nd + 1];
    float4 a0 = {0.f, 0.f, 0.f, 0.f};
    float4 a1 = {0.f, 0.f, 0.f, 0.f};
    float4 a2 = {0.f, 0.f, 0.f, 0.f};
    float4 a3 = {0.f, 0.f, 0.f, 0.f};
    int j = s;
    for (; j + 4 <= e; j += 4) {
        const int i0 = adj[j], i1 = adj[j + 1], i2 = adj[j + 2], i3 = adj[j + 3];
        const float4 v0 = *reinterpret_cast<const float4*>(xin + (size_t)i0 * DD + c);
        const float4 v1 = *reinterpret_cast<const float4*>(xin + (size_t)i1 * DD + c);
        const float4 v2 = *reinterpret_cast<const float4*>(xin + (size_t)i2 * DD + c);
        const float4 v3 = *reinterpret_cast<const float4*>(xin + (size_t)i3 * DD + c);
        a0.x += v0.x; a0.y += v0.y; a0.z += v0.z; a0.w += v0.w;
        a1.x += v1.x; a1.y += v1.y; a1.z += v1.z; a1.w += v1.w;
        a2.x += v2.x; a2.y += v2.y; a2.z += v2.z; a2.w += v2.w;
        a3.x += v3.x; a3.y += v3.y; a3.z += v3.z; a3.w += v3.w;
    }
    for (; j < e; ++j) {
        const float4 v = *reinterpret_cast<const float4*>(xin + (size_t)adj[j] * DD + c);
        a0.x += v.x; a0.y += v.y; a0.z += v.z; a0.w += v.w;
    }
    const int deg = e - s;
    const float inv = (deg > 0) ? (1.0f / (float)deg) : 1.0f;
    float4 r;
    r.x = (a0.x + a1.x + a2.x + a3.x) * inv;
    r.y = (a0.y + a1.y + a2.y + a3.y) * inv;
    r.z = (a0.z + a1.z + a2.z + a3.z) * inv;
    r.w = (a0.w + a1.w + a2.w + a3.w) * inv;
    *reinterpret_cast<float4*>(agg + (size_t)nd * DD + c) = r;
}

// ---------------- W pre-pack into MFMA B-fragment layout, bf16 hi/lo --------
__global__ void pack_B(const float* __restrict__ Wl, const float* __restrict__ Wr,
                       unsigned* __restrict__ Bp, int L) {
    int t = blockIdx.x * 256 + threadIdx.x;
    int wv = t >> 6, lane = t & 63;
    if (wv >= L * 16) return;
    int layer = wv >> 4;
    int fid = wv & 15;
    int ks = fid >> 2, nt = fid & 3;
    int j = nt * 16 + (lane & 15);
    int kb = ks * 32 + (lane >> 4) * 8;
    const float* wl = Wl + (size_t)layer * DD * DD;
    const float* wr = Wr + (size_t)layer * DD * DD;
    unsigned hi[8], lo[8];
#pragma unroll
    for (int s = 0; s < 8; ++s) {
        int k = kb + s;
        float v = (k < DD) ? wl[k * DD + j] : wr[(k - DD) * DD + j];
        unsigned u = __float_as_uint(v);
        unsigned h = u & 0xFFFF0000u;
        hi[s] = h;
        float lf = v - __uint_as_float(h);         // exact residual
        lo[s] = __float_as_uint(lf) & 0xFFFF0000u;
    }
    size_t base_hi = ((size_t)(layer * 2 + 0) * 16 + fid) * 64 + lane;
    size_t base_lo = ((size_t)(layer * 2 + 1) * 16 + fid) * 64 + lane;
#pragma unroll
    for (int p = 0; p < 4; ++p) {
        Bp[base_hi * 4 + p] = (hi[2 * p] >> 16) | hi[2 * p + 1];
        Bp[base_lo * 4 + p] = (lo[2 * p] >> 16) | lo[2 * p + 1];
    }
}

// ---------------- layer GEMM + optional bf16 copy of the output -------------
__global__ __launch_bounds__(256, 2) void mfma_gemm(
    const float* __restrict__ g, const float* __restrict__ x,
    float* __restrict__ out, unsigned short* __restrict__ outb,   // may be null
    const unsigned* __restrict__ Bp, const float* __restrict__ bias, int n) {
    const int lane = threadIdx.x & 63;
    const int wv   = (int)((blockIdx.x * 256 + threadIdx.x) >> 6);
    const int nwv  = (int)((gridDim.x * 256) >> 6);

    short8 Bh[4][4], Bl[4][4];
#pragma unroll
    for (int ks = 0; ks < 4; ++ks)
#pragma unroll
        for (int nt = 0; nt < 4; ++nt) {
            int fid = ks * 4 + nt;
            const uint4 h = *reinterpret_cast<const uint4*>(Bp + ((size_t)fid * 64 + lane) * 4);
            const uint4 l = *reinterpret_cast<const uint4*>(Bp + ((size_t)(16 + fid) * 64 + lane) * 4);
            Bh[ks][nt] = pack4(h.x, h.y, h.z, h.w);
            Bl[ks][nt] = pack4(l.x, l.y, l.z, l.w);
        }

    float bv[4];
#pragma unroll
    for (int nt = 0; nt < 4; ++nt) bv[nt] = bias[nt * 16 + (lane & 15)];

    const int ntiles = (n + 15) >> 4;
    for (int tile = wv; tile < ntiles; tile += nwv) {
        const int row = tile * 16 + (lane & 15);
        const bool ok = row < n;
        const float* grow = g + (size_t)row * DD + (lane >> 4) * 8;
        const float* xrow = x + (size_t)row * DD + (lane >> 4) * 8;

        f32x4 acc[4];
#pragma unroll
        for (int nt = 0; nt < 4; ++nt) acc[nt] = (f32x4){bv[nt], bv[nt], bv[nt], bv[nt]};

#pragma unroll
        for (int ks = 0; ks < 4; ++ks) {
            const float* base = ((ks < 2) ? grow : xrow) + (ks & 1) * 32;
            f32x4 v0 = ok ? *reinterpret_cast<const f32x4*>(base)
                          : (f32x4){0.f, 0.f, 0.f, 0.f};
            f32x4 v1 = ok ? *reinterpret_cast<const f32x4*>(base + 4)
                          : (f32x4){0.f, 0.f, 0.f, 0.f};
            float vv[8] = {v0[0], v0[1], v0[2], v0[3], v1[0], v1[1], v1[2], v1[3]};
            unsigned hu[4], lu[4];
#pragma unroll
            for (int p = 0; p < 4; ++p) {
                unsigned ua = __float_as_uint(vv[2 * p]);
                unsigned ub = __float_as_uint(vv[2 * p + 1]);
                unsigned ha = ua & 0xFFFF0000u, hb = ub & 0xFFFF0000u;
                hu[p] = (ha >> 16) | hb;
                float la = vv[2 * p]     - __uint_as_float(ha);
                float lb = vv[2 * p + 1] - __uint_as_float(hb);
                lu[p] = ((__float_as_uint(la) & 0xFFFF0000u) >> 16) |
                        (__float_as_uint(lb) & 0xFFFF0000u);
            }
            const short8 Ah = pack4(hu[0], hu[1], hu[2], hu[3]);
            const short8 Al = pack4(lu[0], lu[1], lu[2], lu[3]);
#pragma unroll
            for (int nt = 0; nt < 4; ++nt) {
                acc[nt] = __builtin_amdgcn_mfma_f32_16x16x32_bf16(Ah, Bh[ks][nt], acc[nt], 0, 0, 0);
                acc[nt] = __builtin_amdgcn_mfma_f32_16x16x32_bf16(Al, Bh[ks][nt], acc[nt], 0, 0, 0);
                acc[nt] = __builtin_amdgcn_mfma_f32_16x16x32_bf16(Ah, Bl[ks][nt], acc[nt], 0, 0, 0);
            }
        }

        // C/D layout (verified): col = lane&15, row = (lane>>4)*4 + reg
        const int r0 = tile * 16 + (lane >> 4) * 4;
#pragma unroll
        for (int r = 0; r < 4; ++r) {
            const int rr = r0 + r;
            if (rr < n) {
#pragma unroll
                for (int nt = 0; nt < 4; ++nt) {
                    const float v = acc[nt][r];
                    const size_t idx = (size_t)rr * DD + nt * 16 + (lane & 15);
                    out[idx] = v;
                    if (outb) outb[idx] = (unsigned short)rne_bf16(v);
                }
            }
        }
    }
}

// ---------------- pooling partials over TWO arrays at once ----------------
__global__ __launch_bounds__(256) void pool_partial2(
    const float* __restrict__ xa, const float* __restrict__ xb,
    const int* __restrict__ batch,
    float* __restrict__ sumsA, float* __restrict__ sumsB, int n) {
    const int lane = threadIdx.x & 63;
    const int wv   = (int)((blockIdx.x * blockDim.x + threadIdx.x) >> 6);
    const int nwv  = (int)((gridDim.x * blockDim.x) >> 6);
    const int chunk = (n + nwv - 1) / nwv;
    const int start = wv * chunk;
    if (start >= n) return;
    const int end = min(start + chunk, n);

    int g = batch[start];
    float accA = 0.f, accB = 0.f;
    for (int nd = start; nd < end; ++nd) {
        const int bg = batch[nd];
        if (bg != g) {
            atomicAdd(&sumsA[(size_t)g * DD + lane], accA);
            atomicAdd(&sumsB[(size_t)g * DD + lane], accB);
            accA = 0.f; accB = 0.f;
            g = bg;
        }
        accA += xa[(size_t)nd * DD + lane];
        accB += xb[(size_t)nd * DD + lane];
    }
    atomicAdd(&sumsA[(size_t)g * DD + lane], accA);
    atomicAdd(&sumsB[(size_t)g * DD + lane], accB);
}

// ---------------- final: out[g] = mean(agg3)@Wl + mean(x2)@Wr + b ----------
__global__ void final_gemm(const float* __restrict__ sumsA, const float* __restrict__ sumsX,
                           const int* __restrict__ batch,
                           const float* __restrict__ Wl, const float* __restrict__ bl,
                           const float* __restrict__ Wr,
                           float* __restrict__ out, int n) {
    const int g = blockIdx.x;
    const int d = threadIdx.x;  // 64 threads

    int lo = 0, hi = n;
    while (lo < hi) { int m = (lo + hi) >> 1; if (batch[m] < g) lo = m + 1; else hi = m; }
    const int st = lo;
    lo = 0; hi = n;
    while (lo < hi) { int m = (lo + hi) >> 1; if (batch[m] < g + 1) lo = m + 1; else hi = m; }
    const int c = lo - st;

    if (c == 0) {                    // reference: empty graph -> 0 (not bias)
        out[(size_t)g * DD + d] = 0.f;
        return;
    }
    const float inv = 1.0f / (float)c;

    __shared__ float sa[DD], sx[DD];
    sa[d] = sumsA[(size_t)g * DD + d] * inv;
    sx[d] = sumsX[(size_t)g * DD + d] * inv;
    __syncthreads();

    float acc = bl[d];
#pragma unroll 8
    for (int k = 0; k < DD; ++k) acc += sa[k] * Wl[k * DD + d];
#pragma unroll 8
    for (int k = 0; k < DD; ++k) acc += sx[k] * Wr[k * DD + d];
    out[(size_t)g * DD + d] = acc;
}

extern "C" void kernel_launch(void* const* d_in, const int* in_sizes, int n_in,
                              void* d_out, int out_size, void* d_ws, size_t ws_size,
                              hipStream_t stream) {
    const float* x     = (const float*)d_in[0];
    const int*   ei    = (const int*)d_in[1];
    const int*   batch = (const int*)d_in[2];
    const float* Wl    = (const float*)d_in[3];
    const float* bl    = (const float*)d_in[4];
    const float* Wr    = (const float*)d_in[5];

    const int N = in_sizes[0] / DD;
    const int E = in_sizes[1] / 2;
    const int L = in_sizes[3] / (DD * DD);
    const int G = out_size / DD;

    const int* src = ei;        // edge_index[0]
    const int* dst = ei + E;    // edge_index[1]

    char* ws = (char*)d_ws;
    size_t off = 0;
    auto alloc = [&](size_t bytes) -> char* {
        char* p = ws + off;
        off += (bytes + 255) & ~(size_t)255;
        return p;
    };
    int*      deg    = (int*)alloc((size_t)N * 4);
    int*      offs   = (int*)alloc((size_t)(N + 1) * 4);
    int*      cursor = (int*)alloc((size_t)N * 4);
    int*      adj    = (int*)alloc((size_t)E * 4);
    int*      bsum   = (int*)alloc(1024 * 4);
    float*    b0     = (float*)alloc((size_t)N * DD * 4);
    float*    b1     = (float*)alloc((size_t)N * DD * 4);
    float*    aggbuf = (float*)alloc((size_t)N * DD * 4);
    unsigned* Bp     = (unsigned*)alloc((size_t)L * 2 * 16 * 64 * 4 * 4);
    float*    sumsA  = (float*)alloc((size_t)G * DD * 4);
    float*    sumsX  = (float*)alloc((size_t)G * DD * 4);
    // bf16 ping-pong (layer-0 cast aliases slot A; dead before gemm1 writes it)
    const size_t bfbytes = (size_t)N * DD * 2;
    unsigned short* bfA = (unsigned short*)alloc(bfbytes);
    unsigned short* bfB = (unsigned short*)alloc(bfbytes);
    const bool use_bf16 = (off <= ws_size);

    // ---- CSR build, XCD-partitioned (graph reused by all layers) ----
    hipMemsetAsync(deg, 0, (size_t)N * 4, stream);
    count_deg<<<4096, 256, 0, stream>>>(dst, deg, E, N);
    const int nb = (N + 1023) / 1024;
    scan1<<<nb, 1024, 0, stream>>>(deg, offs, bsum, N);
    scan2<<<1, 1024, 0, stream>>>(bsum, nb);
    scan3<<<nb, 1024, 0, stream>>>(offs, bsum, N);
    hipMemcpyAsync(cursor, offs, (size_t)N * 4, hipMemcpyDeviceToDevice, stream);
    fill_adj<<<4096, 256, 0, stream>>>(src, dst, cursor, adj, E, N);

    // ---- pack W into MFMA fragment layout (all layers) ----
    pack_B<<<(L * 16 * 64 + 255) / 256, 256, 0, stream>>>(Wl, Wr, Bp, L);

    // ---- layers 0..L-2: aggregate + MFMA gemm (ping-pong) ----
    const float* cur = x;
    float* bufs[2] = {b0, b1};
    unsigned short* bfs[2] = {bfB, bfA};   // gemm layer l writes bfs[l&1]
    const unsigned short* curb = bfA;      // bf16 view of cur

    if (use_bf16) {
        const long long n8 = (long long)N * DD / 8;
        cast_bf16<<<(int)((n8 + 255) / 256), 256, 0, stream>>>(x, bfA, n8);
    }

    const int aggB_blocks = (N * 8 + 255) / 256;
    const int aggF_blocks = (N * 16 + 255) / 256;
    for (int l = 0; l < L - 1; ++l) {
        float* outb = bufs[l & 1];
        if (use_bf16) {
            aggregate_bf16<<<aggB_blocks, 256, 0, stream>>>(curb, aggbuf, offs, adj, N);
        } else {
            aggregate<<<aggF_blocks, 256, 0, stream>>>(cur, aggbuf, offs, adj, N);
        }
        mfma_gemm<<<1024, 256, 0, stream>>>(aggbuf, cur, outb,
                                            use_bf16 ? bfs[l & 1] : (unsigned short*)nullptr,
                                            Bp + (size_t)l * 2 * 16 * 64 * 4,
                                            bl + (size_t)l * DD, N);
        cur = outb;
        curb = bfs[l & 1];
    }

    // ---- last layer: pooling is linear -> pool(agg), pool(x), tiny GEMM ----
    if (use_bf16) {
        aggregate_bf16<<<aggB_blocks, 256, 0, stream>>>(curb, aggbuf, offs, adj, N);
    } else {
        aggregate<<<aggF_blocks, 256, 0, stream>>>(cur, aggbuf, offs, adj, N);
    }
    hipMemsetAsync(sumsA, 0, (size_t)G * DD * 4, stream);
    hipMemsetAsync(sumsX, 0, (size_t)G * DD * 4, stream);
    pool_partial2<<<2048, 256, 0, stream>>>(aggbuf, cur, batch, sumsA, sumsX, N);
    final_gemm<<<G, DD, 0, stream>>>(sumsA, sumsX, batch,
                                     Wl + (size_t)(L - 1) * DD * DD,
                                     bl + (size_t)(L - 1) * DD,
                                     Wr + (size_t)(L - 1) * DD * DD,
                                     (float*)d_out, N);
}